// Round 6
// baseline (253.918 us; speedup 1.0000x reference)
//
#include <hip/hip_runtime.h>

#define WIDTH  1024
#define HEIGHT 1024
#define NTILE  4

typedef float vfloat4 __attribute__((ext_vector_type(4)));

__global__ __launch_bounds__(256, 4) void fdtd_kernel(
    const float* __restrict__ u1,
    const float* __restrict__ u0,
    const float* __restrict__ j2,
    const float* __restrict__ j0,
    float* __restrict__ out,
    int rowsplit)                               // nrows/NTILE; tile k at row + k*rowsplit
{
    const int row  = blockIdx.x;                // 0 .. rowsplit-1
    const int y    = row & (HEIGHT - 1);        // same y for all tiles (rowsplit % HEIGHT == 0)
    const int lane = threadIdx.x & 63;
    const int x0   = threadIdx.x << 2;          // 4 floats per thread
    const vfloat4 zero = {0.f, 0.f, 0.f, 0.f};

    long base[NTILE];
    base[0] = (long)row * WIDTH + x0;
#pragma unroll
    for (int k = 1; k < NTILE; ++k) base[k] = base[k - 1] + (long)rowsplit * WIDTH;

    // ---- issue ALL vector loads up front (NTILE x 6 x 16B) ----
    vfloat4 c[NTILE], up[NTILE], dn[NTILE], a0[NTILE], v2[NTILE], v0[NTILE];
#pragma unroll
    for (int k = 0; k < NTILE; ++k) {
        const long b = base[k];
        c[k]  = *(const vfloat4*)(u1 + b);
        up[k] = (y > 0)          ? *(const vfloat4*)(u1 + b - WIDTH) : zero;
        dn[k] = (y < HEIGHT - 1) ? *(const vfloat4*)(u1 + b + WIDTH) : zero;
        a0[k] = __builtin_nontemporal_load((const vfloat4*)(u0 + b));
        v2[k] = __builtin_nontemporal_load((const vfloat4*)(j2 + b));
        v0[k] = __builtin_nontemporal_load((const vfloat4*)(j0 + b));
    }

    // ---- x-neighbors: in-register via wave shuffle; wave boundary via scalar load ----
    float lf[NTILE], rt[NTILE];
#pragma unroll
    for (int k = 0; k < NTILE; ++k) {
        lf[k] = __shfl_up(c[k].w, 1);
        rt[k] = __shfl_down(c[k].x, 1);
        if (lane == 0)  lf[k] = (x0 > 0)         ? u1[base[k] - 1] : 0.0f;
        if (lane == 63) rt[k] = (x0 + 4 < WIDTH) ? u1[base[k] + 4] : 0.0f;
    }

    // ---- compute + store ----
#pragma unroll
    for (int k = 0; k < NTILE; ++k) {
        vfloat4 o;
        o.x = 2.0f * c[k].x - a0[k].x + 0.25f * (up[k].x + dn[k].x + lf[k]   + c[k].y - 4.0f * c[k].x)
            - 0.0025f * (v2[k].x - v0[k].x);
        o.y = 2.0f * c[k].y - a0[k].y + 0.25f * (up[k].y + dn[k].y + c[k].x  + c[k].z - 4.0f * c[k].y)
            - 0.0025f * (v2[k].y - v0[k].y);
        o.z = 2.0f * c[k].z - a0[k].z + 0.25f * (up[k].z + dn[k].z + c[k].y  + c[k].w - 4.0f * c[k].z)
            - 0.0025f * (v2[k].z - v0[k].z);
        o.w = 2.0f * c[k].w - a0[k].w + 0.25f * (up[k].w + dn[k].w + c[k].z  + rt[k]  - 4.0f * c[k].w)
            - 0.0025f * (v2[k].w - v0[k].w);
        __builtin_nontemporal_store(o, (vfloat4*)(out + base[k]));
    }
}

extern "C" void kernel_launch(void* const* d_in, const int* in_sizes, int n_in,
                              void* d_out, int out_size, void* d_ws, size_t ws_size,
                              hipStream_t stream) {
    const float* u1 = (const float*)d_in[0];
    const float* u0 = (const float*)d_in[1];
    const float* j2 = (const float*)d_in[2];
    const float* j0 = (const float*)d_in[3];
    float* out = (float*)d_out;

    const int nrows = out_size / WIDTH;         // B*H = 16384
    const int rowsplit = nrows / NTILE;         // 4096
    dim3 block(WIDTH / 4);                      // 256 threads
    dim3 grid(rowsplit);                        // 4096 blocks
    fdtd_kernel<<<grid, block, 0, stream>>>(u1, u0, j2, j0, out, rowsplit);
}